// Round 1
// baseline (3913.144 us; speedup 1.0000x reference)
//
#include <hip/hip_runtime.h>

// GCN 3-layer forward on gfx950.
// Inputs: x[N,128] f32, edge_index[2,E] int32 (harness converts int64->int32),
//         W1[128,128], b1[128], W2[128,128], b2[128], W3[128,64], b3[64]
// out[N,64] f32.
//
// Pipeline per layer: t = h @ W (LDS-tiled fp32 GEMM, ReLU of previous layer
// fused into X-load) ; out = t*dinv^2 + b (init) ; out += scatter-add over
// edges of t[src]*dinv[src]*dinv[dst] (fp32 HW atomics).

#define IN_CH 128

__global__ __launch_bounds__(256) void deg_count(const int* __restrict__ dst,
                                                 float* __restrict__ deg, int E) {
    int e = blockIdx.x * 256 + threadIdx.x;
    if (e < E) unsafeAtomicAdd(&deg[dst[e]], 1.0f);
}

__global__ __launch_bounds__(256) void deg_to_dinv(float* deg, int N) {
    int i = blockIdx.x * 256 + threadIdx.x;
    if (i < N) deg[i] = rsqrtf(deg[i] + 1.0f);
}

// Y[N,FOUT] = (RELU_IN ? relu(X) : X)[N,128] @ W[128,FOUT]
// Block: 256 threads, 64 rows. LDS: X tile 32KB + W 64-col tile 32KB = 64KB.
// Thread computes 4 rows x 4 cols; k unrolled by 4 with float4 LDS reads.
template <int FOUT, bool RELU_IN>
__global__ __launch_bounds__(256) void gemm_k(const float* __restrict__ X,
                                              const float* __restrict__ W,
                                              float* __restrict__ Y, int N) {
    __shared__ float xs[64][128];
    __shared__ float Ws[128][64];
    const int tid = threadIdx.x;
    const int row0 = blockIdx.x * 64;

    // Load X tile: 64 rows x 32 float4
    for (int i = tid; i < 64 * 32; i += 256) {
        int r = i >> 5, c4 = (i & 31) << 2;
        int gr = row0 + r;
        float4 v = make_float4(0.f, 0.f, 0.f, 0.f);
        if (gr < N) v = *(const float4*)(X + (size_t)gr * IN_CH + c4);
        if (RELU_IN) {
            v.x = fmaxf(v.x, 0.f); v.y = fmaxf(v.y, 0.f);
            v.z = fmaxf(v.z, 0.f); v.w = fmaxf(v.w, 0.f);
        }
        *(float4*)(&xs[r][c4]) = v;
    }

    const int c = (tid & 15) << 2;   // col offset within 64-col pass
    const int r = (tid >> 4) << 2;   // 4 rows starting here

    for (int c0 = 0; c0 < FOUT; c0 += 64) {
        __syncthreads();
        // Load W tile: 128 x 16 float4
        for (int i = tid; i < 128 * 16; i += 256) {
            int k = i >> 4, cc = (i & 15) << 2;
            *(float4*)(&Ws[k][cc]) = *(const float4*)(W + (size_t)k * FOUT + c0 + cc);
        }
        __syncthreads();

        float4 acc[4];
        acc[0] = make_float4(0.f, 0.f, 0.f, 0.f);
        acc[1] = acc[0]; acc[2] = acc[0]; acc[3] = acc[0];

#pragma unroll 4
        for (int k = 0; k < 128; k += 4) {
            float4 w0 = *(const float4*)(&Ws[k + 0][c]);
            float4 w1 = *(const float4*)(&Ws[k + 1][c]);
            float4 w2 = *(const float4*)(&Ws[k + 2][c]);
            float4 w3 = *(const float4*)(&Ws[k + 3][c]);
#pragma unroll
            for (int j = 0; j < 4; ++j) {
                float4 xv = *(const float4*)(&xs[r + j][k]);
                acc[j].x += xv.x * w0.x + xv.y * w1.x + xv.z * w2.x + xv.w * w3.x;
                acc[j].y += xv.x * w0.y + xv.y * w1.y + xv.z * w2.y + xv.w * w3.y;
                acc[j].z += xv.x * w0.z + xv.y * w1.z + xv.z * w2.z + xv.w * w3.z;
                acc[j].w += xv.x * w0.w + xv.y * w1.w + xv.z * w2.w + xv.w * w3.w;
            }
        }
#pragma unroll
        for (int j = 0; j < 4; ++j) {
            int gr = row0 + r + j;
            if (gr < N) *(float4*)(Y + (size_t)gr * FOUT + c0 + c) = acc[j];
        }
    }
}

// out[i][f] = T[i][f] * dinv[i]^2 + b[f]
template <int FOUT>
__global__ __launch_bounds__(256) void init_k(const float* __restrict__ T,
                                              const float* __restrict__ dinv,
                                              const float* __restrict__ b,
                                              float* __restrict__ out, int N) {
    const int VPR = FOUT / 4;  // float4 per row
    long long gid = (long long)blockIdx.x * 256 + threadIdx.x;
    long long total = (long long)N * VPR;
    if (gid >= total) return;
    int row = (int)(gid / VPR);
    int c4 = (int)(gid % VPR) << 2;
    float sn = dinv[row];
    sn *= sn;
    float4 t = *(const float4*)(T + (size_t)row * FOUT + c4);
    float4 bb = *(const float4*)(b + c4);
    float4 o;
    o.x = t.x * sn + bb.x; o.y = t.y * sn + bb.y;
    o.z = t.z * sn + bb.z; o.w = t.w * sn + bb.w;
    *(float4*)(out + (size_t)row * FOUT + c4) = o;
}

// out[dst[e]] += T[src[e]] * dinv[src]*dinv[dst], FOUT/4 threads per edge
template <int FOUT>
__global__ __launch_bounds__(256) void scatter_k(const int* __restrict__ src,
                                                 const int* __restrict__ dst,
                                                 const float* __restrict__ dinv,
                                                 const float* __restrict__ T,
                                                 float* __restrict__ out, int E) {
    const int TPE = FOUT / 4;
    long long gid = (long long)blockIdx.x * 256 + threadIdx.x;
    long long e = gid / TPE;
    if (e >= E) return;
    int fo = (int)(gid % TPE) << 2;
    int s = src[e], d = dst[e];
    float nrm = dinv[s] * dinv[d];
    float4 v = *(const float4*)(T + (size_t)s * FOUT + fo);
    float* o = out + (size_t)d * FOUT + fo;
    unsafeAtomicAdd(o + 0, v.x * nrm);
    unsafeAtomicAdd(o + 1, v.y * nrm);
    unsafeAtomicAdd(o + 2, v.z * nrm);
    unsafeAtomicAdd(o + 3, v.w * nrm);
}

extern "C" void kernel_launch(void* const* d_in, const int* in_sizes, int n_in,
                              void* d_out, int out_size, void* d_ws, size_t ws_size,
                              hipStream_t stream) {
    const float* x  = (const float*)d_in[0];
    const int* eidx = (const int*)d_in[1];
    const float* W1 = (const float*)d_in[2];
    const float* b1 = (const float*)d_in[3];
    const float* W2 = (const float*)d_in[4];
    const float* b2 = (const float*)d_in[5];
    const float* W3 = (const float*)d_in[6];
    const float* b3 = (const float*)d_in[7];
    float* out = (float*)d_out;

    const int N = in_sizes[0] / IN_CH;
    const int E = in_sizes[1] / 2;
    const int* src = eidx;
    const int* dst = eidx + E;

    // Workspace layout: dinv[N] | bufA[N*128] | bufB[N*128]
    size_t dinv_bytes = (((size_t)N * 4) + 255) / 256 * 256;
    float* dinv = (float*)d_ws;
    float* bufA = (float*)((char*)d_ws + dinv_bytes);
    float* bufB = bufA + (size_t)N * 128;

    // deg -> dinv
    hipMemsetAsync(dinv, 0, (size_t)N * 4, stream);
    deg_count<<<(E + 255) / 256, 256, 0, stream>>>(dst, dinv, E);
    deg_to_dinv<<<(N + 255) / 256, 256, 0, stream>>>(dinv, N);

    const int gemm_blocks = (N + 63) / 64;
    const long long e128 = (long long)E * 32, e64 = (long long)E * 16;
    const long long n128 = (long long)N * 32, n64 = (long long)N * 16;

    // Layer 1: t = x@W1 -> bufA ; h1 = agg -> bufB (relu deferred to gemm2)
    gemm_k<128, false><<<gemm_blocks, 256, 0, stream>>>(x, W1, bufA, N);
    init_k<128><<<(int)((n128 + 255) / 256), 256, 0, stream>>>(bufA, dinv, b1, bufB, N);
    scatter_k<128><<<(int)((e128 + 255) / 256), 256, 0, stream>>>(src, dst, dinv, bufA, bufB, E);

    // Layer 2: t = relu(h1)@W2 -> bufA ; h2 = agg -> bufB
    gemm_k<128, true><<<gemm_blocks, 256, 0, stream>>>(bufB, W2, bufA, N);
    init_k<128><<<(int)((n128 + 255) / 256), 256, 0, stream>>>(bufA, dinv, b2, bufB, N);
    scatter_k<128><<<(int)((e128 + 255) / 256), 256, 0, stream>>>(src, dst, dinv, bufA, bufB, E);

    // Layer 3: t = relu(h2)@W3 -> bufA ; out = agg -> d_out (no relu)
    gemm_k<64, true><<<gemm_blocks, 256, 0, stream>>>(bufB, W3, bufA, N);
    init_k<64><<<(int)((n64 + 255) / 256), 256, 0, stream>>>(bufA, dinv, b3, out, N);
    scatter_k<64><<<(int)((e64 + 255) / 256), 256, 0, stream>>>(src, dst, dinv, bufA, out, E);
}

// Round 2
// 751.012 us; speedup vs baseline: 5.2105x; 5.2105x over previous
//
#include <hip/hip_runtime.h>

// GCN 3-layer forward on gfx950.
// Round 2: replace per-edge fp32 atomic scatter (1350us/layer, 1.6GB atomic
// write traffic) with CSR (counting-sort by dst) built once per launch, then
// wave-per-row gather with zero atomics, init+bias fused in.

#define IN_CH 128

// ---------------- degree / dinv ----------------
__global__ __launch_bounds__(256) void cnt_k(const int* __restrict__ dst,
                                             int* __restrict__ cnt, int E) {
    int e = blockIdx.x * 256 + threadIdx.x;
    if (e < E) atomicAdd(&cnt[dst[e]], 1);
}

__global__ __launch_bounds__(256) void dinv_k(const int* __restrict__ cnt,
                                              float* __restrict__ dinv, int N) {
    int i = blockIdx.x * 256 + threadIdx.x;
    if (i < N) dinv[i] = rsqrtf((float)cnt[i] + 1.0f);
}

// ---------------- 3-kernel exclusive scan of cnt -> rowptr ----------------
__global__ __launch_bounds__(256) void scan1_k(const int* __restrict__ cnt,
                                               int* __restrict__ bsum, int N) {
    __shared__ int s[256];
    int tid = threadIdx.x;
    int i = blockIdx.x * 256 + tid;
    s[tid] = (i < N) ? cnt[i] : 0;
    __syncthreads();
    for (int off = 128; off > 0; off >>= 1) {
        if (tid < off) s[tid] += s[tid + off];
        __syncthreads();
    }
    if (tid == 0) bsum[blockIdx.x] = s[0];
}

__global__ __launch_bounds__(512) void scan2_k(int* __restrict__ bsum, int nb) {
    __shared__ int s[512];
    __shared__ int carry_s;
    int tid = threadIdx.x;
    if (tid == 0) carry_s = 0;
    __syncthreads();
    for (int base = 0; base < nb; base += 512) {
        int c = carry_s;
        int i = base + tid;
        int v = (i < nb) ? bsum[i] : 0;
        s[tid] = v;
        __syncthreads();
        for (int off = 1; off < 512; off <<= 1) {
            int t = (tid >= off) ? s[tid - off] : 0;
            __syncthreads();
            s[tid] += t;
            __syncthreads();
        }
        if (i < nb) bsum[i] = s[tid] - v + c;  // exclusive + carry
        __syncthreads();
        if (tid == 0) carry_s = c + s[511];
        __syncthreads();
    }
}

__global__ __launch_bounds__(256) void scan3_k(const int* __restrict__ cnt,
                                               const int* __restrict__ bsum,
                                               int* __restrict__ rowptr, int N) {
    __shared__ int s[256];
    int tid = threadIdx.x;
    int i = blockIdx.x * 256 + tid;
    int v = (i < N) ? cnt[i] : 0;
    s[tid] = v;
    __syncthreads();
    for (int off = 1; off < 256; off <<= 1) {
        int t = (tid >= off) ? s[tid - off] : 0;
        __syncthreads();
        s[tid] += t;
        __syncthreads();
    }
    if (i < N) rowptr[i] = s[tid] - v + bsum[blockIdx.x];
}

// fill: rowptr[i] (exclusive start) mutates into row end; csr_src gets src ids
__global__ __launch_bounds__(256) void fill_k(const int* __restrict__ src,
                                              const int* __restrict__ dst,
                                              int* __restrict__ rowptr,
                                              int* __restrict__ csr_src, int E) {
    int e = blockIdx.x * 256 + threadIdx.x;
    if (e < E) {
        int pos = atomicAdd(&rowptr[dst[e]], 1);
        csr_src[pos] = src[e];
    }
}

// ---------------- GEMM: Y = (relu?)X @ W ----------------
template <int FOUT, bool RELU_IN>
__global__ __launch_bounds__(256) void gemm_k(const float* __restrict__ X,
                                              const float* __restrict__ W,
                                              float* __restrict__ Y, int N) {
    __shared__ float xs[64][128];
    __shared__ float Ws[128][64];
    const int tid = threadIdx.x;
    const int row0 = blockIdx.x * 64;

    for (int i = tid; i < 64 * 32; i += 256) {
        int r = i >> 5, c4 = (i & 31) << 2;
        int gr = row0 + r;
        float4 v = make_float4(0.f, 0.f, 0.f, 0.f);
        if (gr < N) v = *(const float4*)(X + (size_t)gr * IN_CH + c4);
        if (RELU_IN) {
            v.x = fmaxf(v.x, 0.f); v.y = fmaxf(v.y, 0.f);
            v.z = fmaxf(v.z, 0.f); v.w = fmaxf(v.w, 0.f);
        }
        *(float4*)(&xs[r][c4]) = v;
    }

    const int c = (tid & 15) << 2;
    const int r = (tid >> 4) << 2;

    for (int c0 = 0; c0 < FOUT; c0 += 64) {
        __syncthreads();
        for (int i = tid; i < 128 * 16; i += 256) {
            int k = i >> 4, cc = (i & 15) << 2;
            *(float4*)(&Ws[k][cc]) = *(const float4*)(W + (size_t)k * FOUT + c0 + cc);
        }
        __syncthreads();

        float4 acc[4];
        acc[0] = make_float4(0.f, 0.f, 0.f, 0.f);
        acc[1] = acc[0]; acc[2] = acc[0]; acc[3] = acc[0];

#pragma unroll 4
        for (int k = 0; k < 128; k += 4) {
            float4 w0 = *(const float4*)(&Ws[k + 0][c]);
            float4 w1 = *(const float4*)(&Ws[k + 1][c]);
            float4 w2 = *(const float4*)(&Ws[k + 2][c]);
            float4 w3 = *(const float4*)(&Ws[k + 3][c]);
#pragma unroll
            for (int j = 0; j < 4; ++j) {
                float4 xv = *(const float4*)(&xs[r + j][k]);
                acc[j].x += xv.x * w0.x + xv.y * w1.x + xv.z * w2.x + xv.w * w3.x;
                acc[j].y += xv.x * w0.y + xv.y * w1.y + xv.z * w2.y + xv.w * w3.y;
                acc[j].z += xv.x * w0.z + xv.y * w1.z + xv.z * w2.z + xv.w * w3.z;
                acc[j].w += xv.x * w0.w + xv.y * w1.w + xv.z * w2.w + xv.w * w3.w;
            }
        }
#pragma unroll
        for (int j = 0; j < 4; ++j) {
            int gr = row0 + r + j;
            if (gr < N) *(float4*)(Y + (size_t)gr * FOUT + c0 + c) = acc[j];
        }
    }
}

// ---------------- aggregation: wave per row, no atomics ----------------
// out[row] = b + T[row]*dinv[row]^2 + sum_e dinv[src_e]*dinv[row]*T[src_e]
template <int FOUT>
__global__ __launch_bounds__(256) void gather_k(const int* __restrict__ rowend,
                                                const int* __restrict__ csr_src,
                                                const float* __restrict__ dinv,
                                                const float* __restrict__ T,
                                                const float* __restrict__ bias,
                                                float* __restrict__ out, int N) {
    const int wave = threadIdx.x >> 6;
    const int lane = threadIdx.x & 63;
    const int row = blockIdx.x * 4 + wave;
    if (row >= N) return;

    const int start = (row == 0) ? 0 : rowend[row - 1];
    const int end = rowend[row];
    const float dr = dinv[row];

    if (FOUT == 128) {
        const float* tp = T + (size_t)row * 128 + lane * 2;
        float2 tv = *(const float2*)tp;
        float2 bb = *(const float2*)(bias + lane * 2);
        float ax = bb.x + tv.x * dr * dr;
        float ay = bb.y + tv.y * dr * dr;

        for (int base = start; base < end; base += 64) {
            int nedge = min(64, end - base);
            int s = 0;
            float ds = 0.f;
            if (base + lane < end) {
                s = csr_src[base + lane];
                ds = dinv[s];
            }
            for (int j = 0; j < nedge; ++j) {
                int sj = __shfl(s, j);
                float nrm = __shfl(ds, j) * dr;
                float2 v = *(const float2*)(T + (size_t)sj * 128 + lane * 2);
                ax += nrm * v.x;
                ay += nrm * v.y;
            }
        }
        float2 o; o.x = ax; o.y = ay;
        *(float2*)(out + (size_t)row * 128 + lane * 2) = o;
    } else {
        float acc = bias[lane] + T[(size_t)row * FOUT + lane] * dr * dr;
        for (int base = start; base < end; base += 64) {
            int nedge = min(64, end - base);
            int s = 0;
            float ds = 0.f;
            if (base + lane < end) {
                s = csr_src[base + lane];
                ds = dinv[s];
            }
            for (int j = 0; j < nedge; ++j) {
                int sj = __shfl(s, j);
                float nrm = __shfl(ds, j) * dr;
                acc += nrm * T[(size_t)sj * FOUT + lane];
            }
        }
        out[(size_t)row * FOUT + lane] = acc;
    }
}

extern "C" void kernel_launch(void* const* d_in, const int* in_sizes, int n_in,
                              void* d_out, int out_size, void* d_ws, size_t ws_size,
                              hipStream_t stream) {
    const float* x  = (const float*)d_in[0];
    const int* eidx = (const int*)d_in[1];
    const float* W1 = (const float*)d_in[2];
    const float* b1 = (const float*)d_in[3];
    const float* W2 = (const float*)d_in[4];
    const float* b2 = (const float*)d_in[5];
    const float* W3 = (const float*)d_in[6];
    const float* b3 = (const float*)d_in[7];
    float* out = (float*)d_out;

    const int N = in_sizes[0] / IN_CH;
    const int E = in_sizes[1] / 2;
    const int* src = eidx;
    const int* dst = eidx + E;

    const int nb = (N + 255) / 256;  // scan blocks

    // Workspace layout (256B-aligned chunks):
    // cnt[N] | rowptr[N] | bsum[nb] | dinv[N] | csr_src[E] | bufA[N*128] | bufB[N*128]
    auto align = [](size_t x) { return (x + 255) / 256 * 256; };
    char* p = (char*)d_ws;
    int* cnt = (int*)p;          p += align((size_t)N * 4);
    int* rowptr = (int*)p;       p += align((size_t)N * 4);
    int* bsum = (int*)p;         p += align((size_t)nb * 4);
    float* dinv = (float*)p;     p += align((size_t)N * 4);
    int* csr_src = (int*)p;      p += align((size_t)E * 4);
    float* bufA = (float*)p;     p += align((size_t)N * 128 * 4);
    float* bufB = (float*)p;

    // ---- CSR build (once; reused by all 3 layers) ----
    hipMemsetAsync(cnt, 0, (size_t)N * 4, stream);
    cnt_k<<<(E + 255) / 256, 256, 0, stream>>>(dst, cnt, E);
    dinv_k<<<nb, 256, 0, stream>>>(cnt, dinv, N);
    scan1_k<<<nb, 256, 0, stream>>>(cnt, bsum, N);
    scan2_k<<<1, 512, 0, stream>>>(bsum, nb);
    scan3_k<<<nb, 256, 0, stream>>>(cnt, bsum, rowptr, N);
    fill_k<<<(E + 255) / 256, 256, 0, stream>>>(src, dst, rowptr, csr_src, E);
    // rowptr[i] now holds END of row i.

    const int gemm_blocks = (N + 63) / 64;
    const int gather_blocks = (N + 3) / 4;

    // Layer 1
    gemm_k<128, false><<<gemm_blocks, 256, 0, stream>>>(x, W1, bufA, N);
    gather_k<128><<<gather_blocks, 256, 0, stream>>>(rowptr, csr_src, dinv, bufA, b1, bufB, N);
    // Layer 2
    gemm_k<128, true><<<gemm_blocks, 256, 0, stream>>>(bufB, W2, bufA, N);
    gather_k<128><<<gather_blocks, 256, 0, stream>>>(rowptr, csr_src, dinv, bufA, b2, bufB, N);
    // Layer 3
    gemm_k<64, true><<<gemm_blocks, 256, 0, stream>>>(bufB, W3, bufA, N);
    gather_k<64><<<gather_blocks, 256, 0, stream>>>(rowptr, csr_src, dinv, bufA, b3, out, N);
}

// Round 3
// 539.974 us; speedup vs baseline: 7.2469x; 1.3908x over previous
//
#include <hip/hip_runtime.h>

// GCN 3-layer forward on gfx950.
// Round 3: replace fp32 vector GEMM (158us each, LDS-conflict+occupancy bound)
// with split-precision bf16 MFMA GEMM (C = AhiBhi + AloBhi + AhiBlo, fp32 acc,
// ~2^-17 rel err). No LDS in GEMM; W pre-transposed+split so all fragments are
// contiguous 16B global loads. Gather epilogue fuses ReLU + hi/lo bf16 split.

#define IN_CH 128

typedef __attribute__((ext_vector_type(8))) short bf16x8;
typedef __attribute__((ext_vector_type(4))) float f32x4;

__device__ inline unsigned short f2bf_rne(float f) {
    unsigned u = __float_as_uint(f);
    unsigned r = (u + 0x7FFFu + ((u >> 16) & 1u)) >> 16;
    return (unsigned short)r;
}
__device__ inline float bf2f(unsigned short h) {
    return __uint_as_float(((unsigned)h) << 16);
}

// ---------------- degree / dinv ----------------
__global__ __launch_bounds__(256) void cnt_k(const int* __restrict__ dst,
                                             int* __restrict__ cnt, int E) {
    int e = blockIdx.x * 256 + threadIdx.x;
    if (e < E) atomicAdd(&cnt[dst[e]], 1);
}

__global__ __launch_bounds__(256) void dinv_k(const int* __restrict__ cnt,
                                              float* __restrict__ dinv, int N) {
    int i = blockIdx.x * 256 + threadIdx.x;
    if (i < N) dinv[i] = rsqrtf((float)cnt[i] + 1.0f);
}

// ---------------- 3-kernel exclusive scan of cnt -> rowptr ----------------
__global__ __launch_bounds__(256) void scan1_k(const int* __restrict__ cnt,
                                               int* __restrict__ bsum, int N) {
    __shared__ int s[256];
    int tid = threadIdx.x;
    int i = blockIdx.x * 256 + tid;
    s[tid] = (i < N) ? cnt[i] : 0;
    __syncthreads();
    for (int off = 128; off > 0; off >>= 1) {
        if (tid < off) s[tid] += s[tid + off];
        __syncthreads();
    }
    if (tid == 0) bsum[blockIdx.x] = s[0];
}

__global__ __launch_bounds__(512) void scan2_k(int* __restrict__ bsum, int nb) {
    __shared__ int s[512];
    __shared__ int carry_s;
    int tid = threadIdx.x;
    if (tid == 0) carry_s = 0;
    __syncthreads();
    for (int base = 0; base < nb; base += 512) {
        int c = carry_s;
        int i = base + tid;
        int v = (i < nb) ? bsum[i] : 0;
        s[tid] = v;
        __syncthreads();
        for (int off = 1; off < 512; off <<= 1) {
            int t = (tid >= off) ? s[tid - off] : 0;
            __syncthreads();
            s[tid] += t;
            __syncthreads();
        }
        if (i < nb) bsum[i] = s[tid] - v + c;
        __syncthreads();
        if (tid == 0) carry_s = c + s[511];
        __syncthreads();
    }
}

__global__ __launch_bounds__(256) void scan3_k(const int* __restrict__ cnt,
                                               const int* __restrict__ bsum,
                                               int* __restrict__ rowptr, int N) {
    __shared__ int s[256];
    int tid = threadIdx.x;
    int i = blockIdx.x * 256 + tid;
    int v = (i < N) ? cnt[i] : 0;
    s[tid] = v;
    __syncthreads();
    for (int off = 1; off < 256; off <<= 1) {
        int t = (tid >= off) ? s[tid - off] : 0;
        __syncthreads();
        s[tid] += t;
        __syncthreads();
    }
    if (i < N) rowptr[i] = s[tid] - v + bsum[blockIdx.x];
}

__global__ __launch_bounds__(256) void fill_k(const int* __restrict__ src,
                                              const int* __restrict__ dst,
                                              int* __restrict__ rowptr,
                                              int* __restrict__ csr_src, int E) {
    int e = blockIdx.x * 256 + threadIdx.x;
    if (e < E) {
        int pos = atomicAdd(&rowptr[dst[e]], 1);
        csr_src[pos] = src[e];
    }
}

// ---------------- conversions ----------------
// x[N][128] fp32 -> Ahi/Alo[Npad][128] bf16 (no relu; layer-1 input)
__global__ __launch_bounds__(256) void convx_k(const float* __restrict__ x,
                                               unsigned short* __restrict__ hi,
                                               unsigned short* __restrict__ lo,
                                               long long total4) {
    long long id = (long long)blockIdx.x * 256 + threadIdx.x;
    if (id >= total4) return;
    float4 v = *(const float4*)(x + id * 4);
    ushort4 h, l;
    h.x = f2bf_rne(v.x); l.x = f2bf_rne(v.x - bf2f(h.x));
    h.y = f2bf_rne(v.y); l.y = f2bf_rne(v.y - bf2f(h.y));
    h.z = f2bf_rne(v.z); l.z = f2bf_rne(v.z - bf2f(h.z));
    h.w = f2bf_rne(v.w); l.w = f2bf_rne(v.w - bf2f(h.w));
    *(ushort4*)(hi + id * 4) = h;
    *(ushort4*)(lo + id * 4) = l;
}

// W[128][FOUT] fp32 -> Wt hi/lo [FOUT][128] bf16 (transpose + split)
__global__ __launch_bounds__(256) void convw_k(const float* __restrict__ W,
                                               unsigned short* __restrict__ hi,
                                               unsigned short* __restrict__ lo,
                                               int FOUT) {
    int id = blockIdx.x * 256 + threadIdx.x;
    if (id >= FOUT * 128) return;
    int n = id >> 7, k = id & 127;
    float v = W[k * FOUT + n];
    unsigned short h = f2bf_rne(v);
    hi[id] = h;
    lo[id] = f2bf_rne(v - bf2f(h));
}

// ---------------- MFMA GEMM: Y[N][FOUT] = A[N][128] @ W[128][FOUT] ----------
// A given as hi/lo bf16 row-major [Npad][128]; W as transposed hi/lo
// Wt[FOUT][128]. Block=256 (4 waves), each wave: 32 rows x FOUT cols.
// 16x16x32 bf16 MFMA, layouts per m89: A[m=lane&15][k=quad*8+j],
// B[k=quad*8+j][n=lane&15] (= Wt[n][k]), C: col=lane&15, row=quad*4+reg.
template <int FOUT>
__global__ __launch_bounds__(256) void mfma_gemm(const unsigned short* __restrict__ Ahi,
                                                 const unsigned short* __restrict__ Alo,
                                                 const unsigned short* __restrict__ Bhi,
                                                 const unsigned short* __restrict__ Blo,
                                                 float* __restrict__ Y, int N) {
    constexpr int NCT = FOUT / 16;
    const int tid = threadIdx.x;
    const int wv = tid >> 6, lane = tid & 63;
    const int quad = lane >> 4, l16 = lane & 15;
    const int row0 = blockIdx.x * 128 + wv * 32;  // rows row0 .. row0+31

    f32x4 acc[2][NCT];
#pragma unroll
    for (int rt = 0; rt < 2; ++rt)
#pragma unroll
        for (int ct = 0; ct < NCT; ++ct)
            acc[rt][ct] = (f32x4){0.f, 0.f, 0.f, 0.f};

#pragma unroll
    for (int ks = 0; ks < 4; ++ks) {
        const int ko = ks * 32 + quad * 8;
        bf16x8 ah0 = *(const bf16x8*)(Ahi + (size_t)(row0 + l16) * 128 + ko);
        bf16x8 ah1 = *(const bf16x8*)(Ahi + (size_t)(row0 + 16 + l16) * 128 + ko);
        bf16x8 al0 = *(const bf16x8*)(Alo + (size_t)(row0 + l16) * 128 + ko);
        bf16x8 al1 = *(const bf16x8*)(Alo + (size_t)(row0 + 16 + l16) * 128 + ko);
#pragma unroll
        for (int ct = 0; ct < NCT; ++ct) {
            bf16x8 bh = *(const bf16x8*)(Bhi + (size_t)(ct * 16 + l16) * 128 + ko);
            bf16x8 bl = *(const bf16x8*)(Blo + (size_t)(ct * 16 + l16) * 128 + ko);
            acc[0][ct] = __builtin_amdgcn_mfma_f32_16x16x32_bf16(ah0, bh, acc[0][ct], 0, 0, 0);
            acc[0][ct] = __builtin_amdgcn_mfma_f32_16x16x32_bf16(al0, bh, acc[0][ct], 0, 0, 0);
            acc[0][ct] = __builtin_amdgcn_mfma_f32_16x16x32_bf16(ah0, bl, acc[0][ct], 0, 0, 0);
            acc[1][ct] = __builtin_amdgcn_mfma_f32_16x16x32_bf16(ah1, bh, acc[1][ct], 0, 0, 0);
            acc[1][ct] = __builtin_amdgcn_mfma_f32_16x16x32_bf16(al1, bh, acc[1][ct], 0, 0, 0);
            acc[1][ct] = __builtin_amdgcn_mfma_f32_16x16x32_bf16(ah1, bl, acc[1][ct], 0, 0, 0);
        }
    }

#pragma unroll
    for (int rt = 0; rt < 2; ++rt) {
        const int rbase = row0 + rt * 16 + quad * 4;
#pragma unroll
        for (int ct = 0; ct < NCT; ++ct) {
            const int col = ct * 16 + l16;
            f32x4 v = acc[rt][ct];
#pragma unroll
            for (int r = 0; r < 4; ++r) {
                if (rbase + r < N) Y[(size_t)(rbase + r) * FOUT + col] = v[r];
            }
        }
    }
}

// ---------------- aggregation: wave per row, no atomics ----------------
// res[row] = b + T[row]*dinv^2 + sum_e dinv[src]*dinv[row]*T[src]
// SPLIT: write relu(res) as hi/lo bf16 (next layer's A); else fp32 out.
template <int FOUT, bool SPLIT>
__global__ __launch_bounds__(256) void gather_k(const int* __restrict__ rowend,
                                                const int* __restrict__ csr_src,
                                                const float* __restrict__ dinv,
                                                const float* __restrict__ T,
                                                const float* __restrict__ bias,
                                                float* __restrict__ out,
                                                unsigned short* __restrict__ outHi,
                                                unsigned short* __restrict__ outLo,
                                                int N) {
    const int wave = threadIdx.x >> 6;
    const int lane = threadIdx.x & 63;
    const int row = blockIdx.x * 4 + wave;
    if (row >= N) return;

    const int start = (row == 0) ? 0 : rowend[row - 1];
    const int end = rowend[row];
    const float dr = dinv[row];

    if (FOUT == 128) {
        float2 tv = *(const float2*)(T + (size_t)row * 128 + lane * 2);
        float2 bb = *(const float2*)(bias + lane * 2);
        float ax = bb.x + tv.x * dr * dr;
        float ay = bb.y + tv.y * dr * dr;

        for (int base = start; base < end; base += 64) {
            int nedge = min(64, end - base);
            int s = 0;
            float ds = 0.f;
            if (base + lane < end) {
                s = csr_src[base + lane];
                ds = dinv[s];
            }
            for (int j = 0; j < nedge; ++j) {
                int sj = __shfl(s, j);
                float nrm = __shfl(ds, j) * dr;
                float2 v = *(const float2*)(T + (size_t)sj * 128 + lane * 2);
                ax += nrm * v.x;
                ay += nrm * v.y;
            }
        }
        if (SPLIT) {
            float vx = fmaxf(ax, 0.f), vy = fmaxf(ay, 0.f);
            ushort2 h, l;
            h.x = f2bf_rne(vx); l.x = f2bf_rne(vx - bf2f(h.x));
            h.y = f2bf_rne(vy); l.y = f2bf_rne(vy - bf2f(h.y));
            *(ushort2*)(outHi + (size_t)row * 128 + lane * 2) = h;
            *(ushort2*)(outLo + (size_t)row * 128 + lane * 2) = l;
        } else {
            float2 o; o.x = ax; o.y = ay;
            *(float2*)(out + (size_t)row * 128 + lane * 2) = o;
        }
    } else {
        float acc = bias[lane] + T[(size_t)row * FOUT + lane] * dr * dr;
        for (int base = start; base < end; base += 64) {
            int nedge = min(64, end - base);
            int s = 0;
            float ds = 0.f;
            if (base + lane < end) {
                s = csr_src[base + lane];
                ds = dinv[s];
            }
            for (int j = 0; j < nedge; ++j) {
                int sj = __shfl(s, j);
                float nrm = __shfl(ds, j) * dr;
                acc += nrm * T[(size_t)sj * FOUT + lane];
            }
        }
        out[(size_t)row * FOUT + lane] = acc;
    }
}

extern "C" void kernel_launch(void* const* d_in, const int* in_sizes, int n_in,
                              void* d_out, int out_size, void* d_ws, size_t ws_size,
                              hipStream_t stream) {
    const float* x  = (const float*)d_in[0];
    const int* eidx = (const int*)d_in[1];
    const float* W1 = (const float*)d_in[2];
    const float* b1 = (const float*)d_in[3];
    const float* W2 = (const float*)d_in[4];
    const float* b2 = (const float*)d_in[5];
    const float* W3 = (const float*)d_in[6];
    const float* b3 = (const float*)d_in[7];
    float* out = (float*)d_out;

    const int N = in_sizes[0] / IN_CH;
    const int E = in_sizes[1] / 2;
    const int* src = eidx;
    const int* dst = eidx + E;
    const int Npad = ((N + 127) / 128) * 128;
    const int nb = (N + 255) / 256;

    // Workspace: cnt[N] rowptr[N] bsum[nb] dinv[N] csr_src[E]
    //            Ahi/Alo[Npad*128]u16  T[Npad*128]f32  Wt hi/lo x3
    auto align = [](size_t v) { return (v + 255) / 256 * 256; };
    char* p = (char*)d_ws;
    int* cnt = (int*)p;            p += align((size_t)N * 4);
    int* rowptr = (int*)p;         p += align((size_t)N * 4);
    int* bsum = (int*)p;           p += align((size_t)nb * 4);
    float* dinv = (float*)p;       p += align((size_t)N * 4);
    int* csr_src = (int*)p;        p += align((size_t)E * 4);
    unsigned short* Ahi = (unsigned short*)p;  p += align((size_t)Npad * 128 * 2);
    unsigned short* Alo = (unsigned short*)p;  p += align((size_t)Npad * 128 * 2);
    float* T = (float*)p;          p += align((size_t)Npad * 128 * 4);
    unsigned short* W1h = (unsigned short*)p;  p += align(128 * 128 * 2);
    unsigned short* W1l = (unsigned short*)p;  p += align(128 * 128 * 2);
    unsigned short* W2h = (unsigned short*)p;  p += align(128 * 128 * 2);
    unsigned short* W2l = (unsigned short*)p;  p += align(128 * 128 * 2);
    unsigned short* W3h = (unsigned short*)p;  p += align(64 * 128 * 2);
    unsigned short* W3l = (unsigned short*)p;

    // ---- CSR build (once) ----
    hipMemsetAsync(cnt, 0, (size_t)N * 4, stream);
    cnt_k<<<(E + 255) / 256, 256, 0, stream>>>(dst, cnt, E);
    dinv_k<<<nb, 256, 0, stream>>>(cnt, dinv, N);
    scan1_k<<<nb, 256, 0, stream>>>(cnt, bsum, N);
    scan2_k<<<1, 512, 0, stream>>>(bsum, nb);
    scan3_k<<<nb, 256, 0, stream>>>(cnt, bsum, rowptr, N);
    fill_k<<<(E + 255) / 256, 256, 0, stream>>>(src, dst, rowptr, csr_src, E);
    // rowptr[i] now holds END of row i.

    // ---- conversions ----
    long long x4 = (long long)N * 32;
    convx_k<<<(int)((x4 + 255) / 256), 256, 0, stream>>>(x, Ahi, Alo, x4);
    convw_k<<<(128 * 128 + 255) / 256, 256, 0, stream>>>(W1, W1h, W1l, 128);
    convw_k<<<(128 * 128 + 255) / 256, 256, 0, stream>>>(W2, W2h, W2l, 128);
    convw_k<<<(64 * 128 + 255) / 256, 256, 0, stream>>>(W3, W3h, W3l, 64);

    const int gemm_blocks = Npad / 128;
    const int gather_blocks = (N + 3) / 4;

    // Layer 1
    mfma_gemm<128><<<gemm_blocks, 256, 0, stream>>>(Ahi, Alo, W1h, W1l, T, N);
    gather_k<128, true><<<gather_blocks, 256, 0, stream>>>(rowptr, csr_src, dinv, T, b1,
                                                           nullptr, Ahi, Alo, N);
    // Layer 2
    mfma_gemm<128><<<gemm_blocks, 256, 0, stream>>>(Ahi, Alo, W2h, W2l, T, N);
    gather_k<128, true><<<gather_blocks, 256, 0, stream>>>(rowptr, csr_src, dinv, T, b2,
                                                           nullptr, Ahi, Alo, N);
    // Layer 3
    mfma_gemm<64><<<gemm_blocks, 256, 0, stream>>>(Ahi, Alo, W3h, W3l, T, N);
    gather_k<64, false><<<gather_blocks, 256, 0, stream>>>(rowptr, csr_src, dinv, T, b3,
                                                           out, nullptr, nullptr, N);
}

// Round 4
// 498.286 us; speedup vs baseline: 7.8532x; 1.0837x over previous
//
#include <hip/hip_runtime.h>

// GCN 3-layer forward on gfx950.
// Round 4: T stored as bf16 hi/lo; gather edge messages read hi only (halves
// the dominant random-gather traffic), self term reads hi+lo (~fp32 exact).
// x->bf16 split fused into layer-1 GEMM (kills convx pass). convw merged.

#define IN_CH 128

typedef __attribute__((ext_vector_type(8))) short bf16x8;
typedef __attribute__((ext_vector_type(4))) float f32x4;

__device__ inline unsigned short f2bf_rne(float f) {
    unsigned u = __float_as_uint(f);
    unsigned r = (u + 0x7FFFu + ((u >> 16) & 1u)) >> 16;
    return (unsigned short)r;
}
__device__ inline float bf2f(unsigned short h) {
    return __uint_as_float(((unsigned)h) << 16);
}

// ---------------- degree / dinv ----------------
__global__ __launch_bounds__(256) void cnt_k(const int* __restrict__ dst,
                                             int* __restrict__ cnt, int E) {
    int e = blockIdx.x * 256 + threadIdx.x;
    if (e < E) atomicAdd(&cnt[dst[e]], 1);
}

__global__ __launch_bounds__(256) void dinv_k(const int* __restrict__ cnt,
                                              float* __restrict__ dinv, int N) {
    int i = blockIdx.x * 256 + threadIdx.x;
    if (i < N) dinv[i] = rsqrtf((float)cnt[i] + 1.0f);
}

// ---------------- 3-kernel exclusive scan of cnt -> rowptr ----------------
__global__ __launch_bounds__(256) void scan1_k(const int* __restrict__ cnt,
                                               int* __restrict__ bsum, int N) {
    __shared__ int s[256];
    int tid = threadIdx.x;
    int i = blockIdx.x * 256 + tid;
    s[tid] = (i < N) ? cnt[i] : 0;
    __syncthreads();
    for (int off = 128; off > 0; off >>= 1) {
        if (tid < off) s[tid] += s[tid + off];
        __syncthreads();
    }
    if (tid == 0) bsum[blockIdx.x] = s[0];
}

__global__ __launch_bounds__(512) void scan2_k(int* __restrict__ bsum, int nb) {
    __shared__ int s[512];
    __shared__ int carry_s;
    int tid = threadIdx.x;
    if (tid == 0) carry_s = 0;
    __syncthreads();
    for (int base = 0; base < nb; base += 512) {
        int c = carry_s;
        int i = base + tid;
        int v = (i < nb) ? bsum[i] : 0;
        s[tid] = v;
        __syncthreads();
        for (int off = 1; off < 512; off <<= 1) {
            int t = (tid >= off) ? s[tid - off] : 0;
            __syncthreads();
            s[tid] += t;
            __syncthreads();
        }
        if (i < nb) bsum[i] = s[tid] - v + c;
        __syncthreads();
        if (tid == 0) carry_s = c + s[511];
        __syncthreads();
    }
}

__global__ __launch_bounds__(256) void scan3_k(const int* __restrict__ cnt,
                                               const int* __restrict__ bsum,
                                               int* __restrict__ rowptr, int N) {
    __shared__ int s[256];
    int tid = threadIdx.x;
    int i = blockIdx.x * 256 + tid;
    int v = (i < N) ? cnt[i] : 0;
    s[tid] = v;
    __syncthreads();
    for (int off = 1; off < 256; off <<= 1) {
        int t = (tid >= off) ? s[tid - off] : 0;
        __syncthreads();
        s[tid] += t;
        __syncthreads();
    }
    if (i < N) rowptr[i] = s[tid] - v + bsum[blockIdx.x];
}

__global__ __launch_bounds__(256) void fill_k(const int* __restrict__ src,
                                              const int* __restrict__ dst,
                                              int* __restrict__ rowptr,
                                              int* __restrict__ csr_src, int E) {
    int e = blockIdx.x * 256 + threadIdx.x;
    if (e < E) {
        int pos = atomicAdd(&rowptr[dst[e]], 1);
        csr_src[pos] = src[e];
    }
}

// ---------------- weight conversion (all 3 in one launch) ----------------
// W[128][FOUT] fp32 -> Wt hi/lo [FOUT][128] bf16 (transpose + split)
__device__ inline void convw_one(const float* W, unsigned short* hi,
                                 unsigned short* lo, int FOUT, int id) {
    int n = id >> 7, k = id & 127;
    float v = W[k * FOUT + n];
    unsigned short h = f2bf_rne(v);
    hi[id] = h;
    lo[id] = f2bf_rne(v - bf2f(h));
}

__global__ __launch_bounds__(256) void convw3_k(
    const float* __restrict__ W1, const float* __restrict__ W2,
    const float* __restrict__ W3,
    unsigned short* __restrict__ W1h, unsigned short* __restrict__ W1l,
    unsigned short* __restrict__ W2h, unsigned short* __restrict__ W2l,
    unsigned short* __restrict__ W3h, unsigned short* __restrict__ W3l) {
    int id = blockIdx.x * 256 + threadIdx.x;
    if (id < 16384) convw_one(W1, W1h, W1l, 128, id);
    else if (id < 32768) convw_one(W2, W2h, W2l, 128, id - 16384);
    else if (id < 40960) convw_one(W3, W3h, W3l, 64, id - 32768);
}

// ---------------- MFMA GEMM: T[N][FOUT] = A[N][128] @ W[128][FOUT] ----------
// A: either fp32 (AF32, layer 1: split in-register) or bf16 hi/lo arrays.
// W as transposed hi/lo Wt[FOUT][128]. Split-precision: C = AhBh + AlBh + AhBl.
// Output written as bf16 hi/lo (Thi, Tlo).
// 16x16x32 layouts (m89): A[m=lane&15][k=quad*8+j], B = Wt[n=lane&15][k],
// C: col=lane&15, row=quad*4+reg.
__device__ inline void split8(const float* __restrict__ p, bf16x8& hi, bf16x8& lo) {
    float4 v0 = *(const float4*)p;
    float4 v1 = *(const float4*)(p + 4);
    float vv[8] = {v0.x, v0.y, v0.z, v0.w, v1.x, v1.y, v1.z, v1.w};
#pragma unroll
    for (int i = 0; i < 8; ++i) {
        unsigned short h = f2bf_rne(vv[i]);
        hi[i] = (short)h;
        lo[i] = (short)f2bf_rne(vv[i] - bf2f(h));
    }
}

template <int FOUT, bool AF32>
__global__ __launch_bounds__(256) void mfma_gemm(const float* __restrict__ Af,
                                                 const unsigned short* __restrict__ Ahi,
                                                 const unsigned short* __restrict__ Alo,
                                                 const unsigned short* __restrict__ Bhi,
                                                 const unsigned short* __restrict__ Blo,
                                                 unsigned short* __restrict__ Thi,
                                                 unsigned short* __restrict__ Tlo,
                                                 int N) {
    constexpr int NCT = FOUT / 16;
    const int tid = threadIdx.x;
    const int wv = tid >> 6, lane = tid & 63;
    const int quad = lane >> 4, l16 = lane & 15;
    const int row0 = blockIdx.x * 128 + wv * 32;  // rows row0 .. row0+31

    f32x4 acc[2][NCT];
#pragma unroll
    for (int rt = 0; rt < 2; ++rt)
#pragma unroll
        for (int ct = 0; ct < NCT; ++ct)
            acc[rt][ct] = (f32x4){0.f, 0.f, 0.f, 0.f};

    // clamped rows for the fp32 path (x has exactly N rows; pad tile would OOB)
    const int ra = AF32 ? min(row0 + l16, N - 1) : (row0 + l16);
    const int rb = AF32 ? min(row0 + 16 + l16, N - 1) : (row0 + 16 + l16);

#pragma unroll
    for (int ks = 0; ks < 4; ++ks) {
        const int ko = ks * 32 + quad * 8;
        bf16x8 ah0, ah1, al0, al1;
        if (AF32) {
            split8(Af + (size_t)ra * 128 + ko, ah0, al0);
            split8(Af + (size_t)rb * 128 + ko, ah1, al1);
        } else {
            ah0 = *(const bf16x8*)(Ahi + (size_t)(row0 + l16) * 128 + ko);
            ah1 = *(const bf16x8*)(Ahi + (size_t)(row0 + 16 + l16) * 128 + ko);
            al0 = *(const bf16x8*)(Alo + (size_t)(row0 + l16) * 128 + ko);
            al1 = *(const bf16x8*)(Alo + (size_t)(row0 + 16 + l16) * 128 + ko);
        }
#pragma unroll
        for (int ct = 0; ct < NCT; ++ct) {
            bf16x8 bh = *(const bf16x8*)(Bhi + (size_t)(ct * 16 + l16) * 128 + ko);
            bf16x8 bl = *(const bf16x8*)(Blo + (size_t)(ct * 16 + l16) * 128 + ko);
            acc[0][ct] = __builtin_amdgcn_mfma_f32_16x16x32_bf16(ah0, bh, acc[0][ct], 0, 0, 0);
            acc[0][ct] = __builtin_amdgcn_mfma_f32_16x16x32_bf16(al0, bh, acc[0][ct], 0, 0, 0);
            acc[0][ct] = __builtin_amdgcn_mfma_f32_16x16x32_bf16(ah0, bl, acc[0][ct], 0, 0, 0);
            acc[1][ct] = __builtin_amdgcn_mfma_f32_16x16x32_bf16(ah1, bh, acc[1][ct], 0, 0, 0);
            acc[1][ct] = __builtin_amdgcn_mfma_f32_16x16x32_bf16(al1, bh, acc[1][ct], 0, 0, 0);
            acc[1][ct] = __builtin_amdgcn_mfma_f32_16x16x32_bf16(ah1, bl, acc[1][ct], 0, 0, 0);
        }
    }

#pragma unroll
    for (int rt = 0; rt < 2; ++rt) {
        const int rbase = row0 + rt * 16 + quad * 4;
#pragma unroll
        for (int ct = 0; ct < NCT; ++ct) {
            const int col = ct * 16 + l16;
            f32x4 v = acc[rt][ct];
#pragma unroll
            for (int r = 0; r < 4; ++r) {
                if (rbase + r < N) {
                    size_t idx = (size_t)(rbase + r) * FOUT + col;
                    unsigned short h = f2bf_rne(v[r]);
                    Thi[idx] = h;
                    Tlo[idx] = f2bf_rne(v[r] - bf2f(h));
                }
            }
        }
    }
}

// ---------------- aggregation: wave per row, no atomics ----------------
// res[row] = b + (Thi+Tlo)[row]*dinv^2 + sum_e dinv[src]*dinv[row]*Thi[src]
// SPLIT: write relu(res) as hi/lo bf16 (next layer's A); else fp32 out.
template <int FOUT, bool SPLIT>
__global__ __launch_bounds__(256) void gather_k(const int* __restrict__ rowend,
                                                const int* __restrict__ csr_src,
                                                const float* __restrict__ dinv,
                                                const unsigned short* __restrict__ Thi,
                                                const unsigned short* __restrict__ Tlo,
                                                const float* __restrict__ bias,
                                                float* __restrict__ out,
                                                unsigned short* __restrict__ outHi,
                                                unsigned short* __restrict__ outLo,
                                                int N) {
    const int wave = threadIdx.x >> 6;
    const int lane = threadIdx.x & 63;
    const int row = blockIdx.x * 4 + wave;
    if (row >= N) return;

    const int start = (row == 0) ? 0 : rowend[row - 1];
    const int end = rowend[row];
    const float dr = dinv[row];

    if (FOUT == 128) {
        const unsigned* thi32 = (const unsigned*)Thi;  // bf16x2, row stride 64
        const unsigned* tlo32 = (const unsigned*)Tlo;
        unsigned sh = thi32[(size_t)row * 64 + lane];
        unsigned sl = tlo32[(size_t)row * 64 + lane];
        float2 bb = *(const float2*)(bias + lane * 2);
        float sx = bf2f((unsigned short)(sh & 0xffff)) + bf2f((unsigned short)(sl & 0xffff));
        float sy = bf2f((unsigned short)(sh >> 16)) + bf2f((unsigned short)(sl >> 16));
        float ax = bb.x + sx * dr * dr;
        float ay = bb.y + sy * dr * dr;

        for (int base = start; base < end; base += 64) {
            int nedge = min(64, end - base);
            int s = 0;
            float ds = 0.f;
            if (base + lane < end) {
                s = csr_src[base + lane];
                ds = dinv[s];
            }
            for (int j = 0; j < nedge; ++j) {
                int sj = __shfl(s, j);
                float nrm = __shfl(ds, j) * dr;
                unsigned mv = thi32[(size_t)sj * 64 + lane];
                ax += nrm * bf2f((unsigned short)(mv & 0xffff));
                ay += nrm * bf2f((unsigned short)(mv >> 16));
            }
        }
        if (SPLIT) {
            float vx = fmaxf(ax, 0.f), vy = fmaxf(ay, 0.f);
            ushort2 h, l;
            h.x = f2bf_rne(vx); l.x = f2bf_rne(vx - bf2f(h.x));
            h.y = f2bf_rne(vy); l.y = f2bf_rne(vy - bf2f(h.y));
            *(ushort2*)(outHi + (size_t)row * 128 + lane * 2) = h;
            *(ushort2*)(outLo + (size_t)row * 128 + lane * 2) = l;
        } else {
            float2 o; o.x = ax; o.y = ay;
            *(float2*)(out + (size_t)row * 128 + lane * 2) = o;
        }
    } else {
        float self = bf2f(Thi[(size_t)row * FOUT + lane]) + bf2f(Tlo[(size_t)row * FOUT + lane]);
        float acc = bias[lane] + self * dr * dr;
        for (int base = start; base < end; base += 64) {
            int nedge = min(64, end - base);
            int s = 0;
            float ds = 0.f;
            if (base + lane < end) {
                s = csr_src[base + lane];
                ds = dinv[s];
            }
            for (int j = 0; j < nedge; ++j) {
                int sj = __shfl(s, j);
                float nrm = __shfl(ds, j) * dr;
                acc += nrm * bf2f(Thi[(size_t)sj * FOUT + lane]);
            }
        }
        out[(size_t)row * FOUT + lane] = acc;
    }
}

extern "C" void kernel_launch(void* const* d_in, const int* in_sizes, int n_in,
                              void* d_out, int out_size, void* d_ws, size_t ws_size,
                              hipStream_t stream) {
    const float* x  = (const float*)d_in[0];
    const int* eidx = (const int*)d_in[1];
    const float* W1 = (const float*)d_in[2];
    const float* b1 = (const float*)d_in[3];
    const float* W2 = (const float*)d_in[4];
    const float* b2 = (const float*)d_in[5];
    const float* W3 = (const float*)d_in[6];
    const float* b3 = (const float*)d_in[7];
    float* out = (float*)d_out;

    const int N = in_sizes[0] / IN_CH;
    const int E = in_sizes[1] / 2;
    const int* src = eidx;
    const int* dst = eidx + E;
    const int Npad = ((N + 127) / 128) * 128;
    const int nb = (N + 255) / 256;

    auto align = [](size_t v) { return (v + 255) / 256 * 256; };
    char* p = (char*)d_ws;
    int* cnt = (int*)p;            p += align((size_t)N * 4);
    int* rowptr = (int*)p;         p += align((size_t)N * 4);
    int* bsum = (int*)p;           p += align((size_t)nb * 4);
    float* dinv = (float*)p;       p += align((size_t)N * 4);
    int* csr_src = (int*)p;        p += align((size_t)E * 4);
    unsigned short* Ahi = (unsigned short*)p;  p += align((size_t)Npad * 128 * 2);
    unsigned short* Alo = (unsigned short*)p;  p += align((size_t)Npad * 128 * 2);
    unsigned short* Thi = (unsigned short*)p;  p += align((size_t)Npad * 128 * 2);
    unsigned short* Tlo = (unsigned short*)p;  p += align((size_t)Npad * 128 * 2);
    unsigned short* W1h = (unsigned short*)p;  p += align(128 * 128 * 2);
    unsigned short* W1l = (unsigned short*)p;  p += align(128 * 128 * 2);
    unsigned short* W2h = (unsigned short*)p;  p += align(128 * 128 * 2);
    unsigned short* W2l = (unsigned short*)p;  p += align(128 * 128 * 2);
    unsigned short* W3h = (unsigned short*)p;  p += align(64 * 128 * 2);
    unsigned short* W3l = (unsigned short*)p;

    // ---- CSR build (once) ----
    hipMemsetAsync(cnt, 0, (size_t)N * 4, stream);
    cnt_k<<<(E + 255) / 256, 256, 0, stream>>>(dst, cnt, E);
    dinv_k<<<nb, 256, 0, stream>>>(cnt, dinv, N);
    scan1_k<<<nb, 256, 0, stream>>>(cnt, bsum, N);
    scan2_k<<<1, 512, 0, stream>>>(bsum, nb);
    scan3_k<<<nb, 256, 0, stream>>>(cnt, bsum, rowptr, N);
    fill_k<<<(E + 255) / 256, 256, 0, stream>>>(src, dst, rowptr, csr_src, E);
    // rowptr[i] now holds END of row i.

    convw3_k<<<160, 256, 0, stream>>>(W1, W2, W3, W1h, W1l, W2h, W2l, W3h, W3l);

    const int gemm_blocks = Npad / 128;
    const int gather_blocks = (N + 3) / 4;

    // Layer 1 (A = x fp32, split in-register)
    mfma_gemm<128, true><<<gemm_blocks, 256, 0, stream>>>(x, nullptr, nullptr,
                                                          W1h, W1l, Thi, Tlo, N);
    gather_k<128, true><<<gather_blocks, 256, 0, stream>>>(rowptr, csr_src, dinv, Thi, Tlo,
                                                           b1, nullptr, Ahi, Alo, N);
    // Layer 2
    mfma_gemm<128, false><<<gemm_blocks, 256, 0, stream>>>(nullptr, Ahi, Alo,
                                                           W2h, W2l, Thi, Tlo, N);
    gather_k<128, true><<<gather_blocks, 256, 0, stream>>>(rowptr, csr_src, dinv, Thi, Tlo,
                                                           b2, nullptr, Ahi, Alo, N);
    // Layer 3
    mfma_gemm<64, false><<<gemm_blocks, 256, 0, stream>>>(nullptr, Ahi, Alo,
                                                          W3h, W3l, Thi, Tlo, N);
    gather_k<64, false><<<gather_blocks, 256, 0, stream>>>(rowptr, csr_src, dinv, Thi, Tlo,
                                                           b3, out, nullptr, nullptr, N);
}

// Round 5
// 456.847 us; speedup vs baseline: 8.5656x; 1.0907x over previous
//
#include <hip/hip_runtime.h>

// GCN 3-layer forward on gfx950.
// Round 5: gather inner loop de-overheaded. fill_k precomputes (src, norm)
// int2 pairs (norm = dinv[src]*dinv[dst]); gather reads pairs via wave-uniform
// broadcast loads (no shfl/ds_bpermute, no dinv gather) and unrolls 4 edges
// with independent row loads for MLP.

#define IN_CH 128

typedef __attribute__((ext_vector_type(8))) short bf16x8;
typedef __attribute__((ext_vector_type(4))) float f32x4;

__device__ inline unsigned short f2bf_rne(float f) {
    unsigned u = __float_as_uint(f);
    unsigned r = (u + 0x7FFFu + ((u >> 16) & 1u)) >> 16;
    return (unsigned short)r;
}
__device__ inline float bf2f(unsigned short h) {
    return __uint_as_float(((unsigned)h) << 16);
}
__device__ inline float bf2f_lo(unsigned m) {  // low bf16 of packed pair
    return __uint_as_float(m << 16);
}
__device__ inline float bf2f_hi(unsigned m) {  // high bf16 of packed pair
    return __uint_as_float(m & 0xffff0000u);
}

// ---------------- degree count ----------------
__global__ __launch_bounds__(256) void cnt_k(const int* __restrict__ dst,
                                             int* __restrict__ cnt, int E) {
    int e = blockIdx.x * 256 + threadIdx.x;
    if (e < E) atomicAdd(&cnt[dst[e]], 1);
}

// ---------------- scan stage 1 (+ dinv fused) ----------------
__global__ __launch_bounds__(256) void scan1_k(const int* __restrict__ cnt,
                                               int* __restrict__ bsum,
                                               float* __restrict__ dinv, int N) {
    __shared__ int s[256];
    int tid = threadIdx.x;
    int i = blockIdx.x * 256 + tid;
    int v = (i < N) ? cnt[i] : 0;
    if (i < N) dinv[i] = rsqrtf((float)v + 1.0f);
    s[tid] = v;
    __syncthreads();
    for (int off = 128; off > 0; off >>= 1) {
        if (tid < off) s[tid] += s[tid + off];
        __syncthreads();
    }
    if (tid == 0) bsum[blockIdx.x] = s[0];
}

__global__ __launch_bounds__(512) void scan2_k(int* __restrict__ bsum, int nb) {
    __shared__ int s[512];
    __shared__ int carry_s;
    int tid = threadIdx.x;
    if (tid == 0) carry_s = 0;
    __syncthreads();
    for (int base = 0; base < nb; base += 512) {
        int c = carry_s;
        int i = base + tid;
        int v = (i < nb) ? bsum[i] : 0;
        s[tid] = v;
        __syncthreads();
        for (int off = 1; off < 512; off <<= 1) {
            int t = (tid >= off) ? s[tid - off] : 0;
            __syncthreads();
            s[tid] += t;
            __syncthreads();
        }
        if (i < nb) bsum[i] = s[tid] - v + c;
        __syncthreads();
        if (tid == 0) carry_s = c + s[511];
        __syncthreads();
    }
}

__global__ __launch_bounds__(256) void scan3_k(const int* __restrict__ cnt,
                                               const int* __restrict__ bsum,
                                               int* __restrict__ rowptr, int N) {
    __shared__ int s[256];
    int tid = threadIdx.x;
    int i = blockIdx.x * 256 + tid;
    int v = (i < N) ? cnt[i] : 0;
    s[tid] = v;
    __syncthreads();
    for (int off = 1; off < 256; off <<= 1) {
        int t = (tid >= off) ? s[tid - off] : 0;
        __syncthreads();
        s[tid] += t;
        __syncthreads();
    }
    if (i < N) rowptr[i] = s[tid] - v + bsum[blockIdx.x];
}

// fill: pairs[pos] = (src, dinv[src]*dinv[dst]); rowptr mutates into row end
__global__ __launch_bounds__(256) void fill_k(const int* __restrict__ src,
                                              const int* __restrict__ dst,
                                              const float* __restrict__ dinv,
                                              int* __restrict__ rowptr,
                                              int2* __restrict__ pairs, int E) {
    int e = blockIdx.x * 256 + threadIdx.x;
    if (e < E) {
        int s = src[e], d = dst[e];
        float nrm = dinv[s] * dinv[d];
        int pos = atomicAdd(&rowptr[d], 1);
        pairs[pos] = make_int2(s, __float_as_int(nrm));
    }
}

// ---------------- weight conversion (all 3 in one launch) ----------------
__device__ inline void convw_one(const float* W, unsigned short* hi,
                                 unsigned short* lo, int FOUT, int id) {
    int n = id >> 7, k = id & 127;
    float v = W[k * FOUT + n];
    unsigned short h = f2bf_rne(v);
    hi[id] = h;
    lo[id] = f2bf_rne(v - bf2f(h));
}

__global__ __launch_bounds__(256) void convw3_k(
    const float* __restrict__ W1, const float* __restrict__ W2,
    const float* __restrict__ W3,
    unsigned short* __restrict__ W1h, unsigned short* __restrict__ W1l,
    unsigned short* __restrict__ W2h, unsigned short* __restrict__ W2l,
    unsigned short* __restrict__ W3h, unsigned short* __restrict__ W3l) {
    int id = blockIdx.x * 256 + threadIdx.x;
    if (id < 16384) convw_one(W1, W1h, W1l, 128, id);
    else if (id < 32768) convw_one(W2, W2h, W2l, 128, id - 16384);
    else if (id < 40960) convw_one(W3, W3h, W3l, 64, id - 32768);
}

// ---------------- MFMA GEMM: T[N][FOUT] = A[N][128] @ W[128][FOUT] ----------
// Split-precision bf16: C = AhBh + AlBh + AhBl (fp32 acc). Output bf16 hi/lo.
// 16x16x32 layouts (m89): A[m=lane&15][k=quad*8+j], B = Wt[n=lane&15][k],
// C: col=lane&15, row=quad*4+reg.
__device__ inline void split8(const float* __restrict__ p, bf16x8& hi, bf16x8& lo) {
    float4 v0 = *(const float4*)p;
    float4 v1 = *(const float4*)(p + 4);
    float vv[8] = {v0.x, v0.y, v0.z, v0.w, v1.x, v1.y, v1.z, v1.w};
#pragma unroll
    for (int i = 0; i < 8; ++i) {
        unsigned short h = f2bf_rne(vv[i]);
        hi[i] = (short)h;
        lo[i] = (short)f2bf_rne(vv[i] - bf2f(h));
    }
}

template <int FOUT, bool AF32>
__global__ __launch_bounds__(256) void mfma_gemm(const float* __restrict__ Af,
                                                 const unsigned short* __restrict__ Ahi,
                                                 const unsigned short* __restrict__ Alo,
                                                 const unsigned short* __restrict__ Bhi,
                                                 const unsigned short* __restrict__ Blo,
                                                 unsigned short* __restrict__ Thi,
                                                 unsigned short* __restrict__ Tlo,
                                                 int N) {
    constexpr int NCT = FOUT / 16;
    const int tid = threadIdx.x;
    const int wv = tid >> 6, lane = tid & 63;
    const int quad = lane >> 4, l16 = lane & 15;
    const int row0 = blockIdx.x * 128 + wv * 32;

    f32x4 acc[2][NCT];
#pragma unroll
    for (int rt = 0; rt < 2; ++rt)
#pragma unroll
        for (int ct = 0; ct < NCT; ++ct)
            acc[rt][ct] = (f32x4){0.f, 0.f, 0.f, 0.f};

    const int ra = AF32 ? min(row0 + l16, N - 1) : (row0 + l16);
    const int rb = AF32 ? min(row0 + 16 + l16, N - 1) : (row0 + 16 + l16);

#pragma unroll
    for (int ks = 0; ks < 4; ++ks) {
        const int ko = ks * 32 + quad * 8;
        bf16x8 ah0, ah1, al0, al1;
        if (AF32) {
            split8(Af + (size_t)ra * 128 + ko, ah0, al0);
            split8(Af + (size_t)rb * 128 + ko, ah1, al1);
        } else {
            ah0 = *(const bf16x8*)(Ahi + (size_t)(row0 + l16) * 128 + ko);
            ah1 = *(const bf16x8*)(Ahi + (size_t)(row0 + 16 + l16) * 128 + ko);
            al0 = *(const bf16x8*)(Alo + (size_t)(row0 + l16) * 128 + ko);
            al1 = *(const bf16x8*)(Alo + (size_t)(row0 + 16 + l16) * 128 + ko);
        }
#pragma unroll
        for (int ct = 0; ct < NCT; ++ct) {
            bf16x8 bh = *(const bf16x8*)(Bhi + (size_t)(ct * 16 + l16) * 128 + ko);
            bf16x8 bl = *(const bf16x8*)(Blo + (size_t)(ct * 16 + l16) * 128 + ko);
            acc[0][ct] = __builtin_amdgcn_mfma_f32_16x16x32_bf16(ah0, bh, acc[0][ct], 0, 0, 0);
            acc[0][ct] = __builtin_amdgcn_mfma_f32_16x16x32_bf16(al0, bh, acc[0][ct], 0, 0, 0);
            acc[0][ct] = __builtin_amdgcn_mfma_f32_16x16x32_bf16(ah0, bl, acc[0][ct], 0, 0, 0);
            acc[1][ct] = __builtin_amdgcn_mfma_f32_16x16x32_bf16(ah1, bh, acc[1][ct], 0, 0, 0);
            acc[1][ct] = __builtin_amdgcn_mfma_f32_16x16x32_bf16(al1, bh, acc[1][ct], 0, 0, 0);
            acc[1][ct] = __builtin_amdgcn_mfma_f32_16x16x32_bf16(ah1, bl, acc[1][ct], 0, 0, 0);
        }
    }

#pragma unroll
    for (int rt = 0; rt < 2; ++rt) {
        const int rbase = row0 + rt * 16 + quad * 4;
#pragma unroll
        for (int ct = 0; ct < NCT; ++ct) {
            const int col = ct * 16 + l16;
            f32x4 v = acc[rt][ct];
#pragma unroll
            for (int r = 0; r < 4; ++r) {
                if (rbase + r < N) {
                    size_t idx = (size_t)(rbase + r) * FOUT + col;
                    unsigned short h = f2bf_rne(v[r]);
                    Thi[idx] = h;
                    Tlo[idx] = f2bf_rne(v[r] - bf2f(h));
                }
            }
        }
    }
}

// ---------------- aggregation: wave per row, no atomics, no shfl ----------
// res[row] = b + (Thi+Tlo)[row]*dinv^2 + sum_e norm_e * Thi[src_e]
template <int FOUT, bool SPLIT>
__global__ __launch_bounds__(256) void gather_k(const int* __restrict__ rowend,
                                                const int2* __restrict__ pairs,
                                                const float* __restrict__ dinv,
                                                const unsigned short* __restrict__ Thi,
                                                const unsigned short* __restrict__ Tlo,
                                                const float* __restrict__ bias,
                                                float* __restrict__ out,
                                                unsigned short* __restrict__ outHi,
                                                unsigned short* __restrict__ outLo,
                                                int N) {
    const int wave = threadIdx.x >> 6;
    const int lane = threadIdx.x & 63;
    const int row = blockIdx.x * 4 + wave;
    if (row >= N) return;

    const int start = (row == 0) ? 0 : rowend[row - 1];
    const int end = rowend[row];
    const float dr = dinv[row];

    if (FOUT == 128) {
        const unsigned* thi32 = (const unsigned*)Thi;  // bf16x2 per dword
        const unsigned* tlo32 = (const unsigned*)Tlo;
        unsigned sh = thi32[(size_t)row * 64 + lane];
        unsigned sl = tlo32[(size_t)row * 64 + lane];
        float2 bb = *(const float2*)(bias + lane * 2);
        float ax = bb.x + (bf2f_lo(sh) + bf2f_lo(sl)) * dr * dr;
        float ay = bb.y + (bf2f_hi(sh) + bf2f_hi(sl)) * dr * dr;

        int j = start;
        if ((j & 1) && j < end) {  // align to even for int4 pair loads
            int2 pv = pairs[j];
            unsigned m = thi32[(size_t)pv.x * 64 + lane];
            float n = __int_as_float(pv.y);
            ax += n * bf2f_lo(m);
            ay += n * bf2f_hi(m);
            ++j;
        }
        for (; j + 4 <= end; j += 4) {
            int4 p01 = *(const int4*)(pairs + j);      // edges j, j+1
            int4 p23 = *(const int4*)(pairs + j + 2);  // edges j+2, j+3
            unsigned m0 = thi32[(size_t)p01.x * 64 + lane];
            unsigned m1 = thi32[(size_t)p01.z * 64 + lane];
            unsigned m2 = thi32[(size_t)p23.x * 64 + lane];
            unsigned m3 = thi32[(size_t)p23.z * 64 + lane];
            float n0 = __int_as_float(p01.y), n1 = __int_as_float(p01.w);
            float n2 = __int_as_float(p23.y), n3 = __int_as_float(p23.w);
            ax += n0 * bf2f_lo(m0); ay += n0 * bf2f_hi(m0);
            ax += n1 * bf2f_lo(m1); ay += n1 * bf2f_hi(m1);
            ax += n2 * bf2f_lo(m2); ay += n2 * bf2f_hi(m2);
            ax += n3 * bf2f_lo(m3); ay += n3 * bf2f_hi(m3);
        }
        for (; j < end; ++j) {
            int2 pv = pairs[j];
            unsigned m = thi32[(size_t)pv.x * 64 + lane];
            float n = __int_as_float(pv.y);
            ax += n * bf2f_lo(m);
            ay += n * bf2f_hi(m);
        }

        if (SPLIT) {
            float vx = fmaxf(ax, 0.f), vy = fmaxf(ay, 0.f);
            ushort2 h, l;
            h.x = f2bf_rne(vx); l.x = f2bf_rne(vx - bf2f(h.x));
            h.y = f2bf_rne(vy); l.y = f2bf_rne(vy - bf2f(h.y));
            *(ushort2*)(outHi + (size_t)row * 128 + lane * 2) = h;
            *(ushort2*)(outLo + (size_t)row * 128 + lane * 2) = l;
        } else {
            float2 o; o.x = ax; o.y = ay;
            *(float2*)(out + (size_t)row * 128 + lane * 2) = o;
        }
    } else {
        float self = bf2f(Thi[(size_t)row * FOUT + lane]) + bf2f(Tlo[(size_t)row * FOUT + lane]);
        float acc = bias[lane] + self * dr * dr;

        int j = start;
        if ((j & 1) && j < end) {
            int2 pv = pairs[j];
            acc += __int_as_float(pv.y) * bf2f(Thi[(size_t)pv.x * FOUT + lane]);
            ++j;
        }
        for (; j + 4 <= end; j += 4) {
            int4 p01 = *(const int4*)(pairs + j);
            int4 p23 = *(const int4*)(pairs + j + 2);
            float m0 = bf2f(Thi[(size_t)p01.x * FOUT + lane]);
            float m1 = bf2f(Thi[(size_t)p01.z * FOUT + lane]);
            float m2 = bf2f(Thi[(size_t)p23.x * FOUT + lane]);
            float m3 = bf2f(Thi[(size_t)p23.z * FOUT + lane]);
            acc += __int_as_float(p01.y) * m0 + __int_as_float(p01.w) * m1 +
                   __int_as_float(p23.y) * m2 + __int_as_float(p23.w) * m3;
        }
        for (; j < end; ++j) {
            int2 pv = pairs[j];
            acc += __int_as_float(pv.y) * bf2f(Thi[(size_t)pv.x * FOUT + lane]);
        }
        out[(size_t)row * FOUT + lane] = acc;
    }
}

extern "C" void kernel_launch(void* const* d_in, const int* in_sizes, int n_in,
                              void* d_out, int out_size, void* d_ws, size_t ws_size,
                              hipStream_t stream) {
    const float* x  = (const float*)d_in[0];
    const int* eidx = (const int*)d_in[1];
    const float* W1 = (const float*)d_in[2];
    const float* b1 = (const float*)d_in[3];
    const float* W2 = (const float*)d_in[4];
    const float* b2 = (const float*)d_in[5];
    const float* W3 = (const float*)d_in[6];
    const float* b3 = (const float*)d_in[7];
    float* out = (float*)d_out;

    const int N = in_sizes[0] / IN_CH;
    const int E = in_sizes[1] / 2;
    const int* src = eidx;
    const int* dst = eidx + E;
    const int Npad = ((N + 127) / 128) * 128;
    const int nb = (N + 255) / 256;

    auto align = [](size_t v) { return (v + 255) / 256 * 256; };
    char* p = (char*)d_ws;
    int* cnt = (int*)p;            p += align((size_t)N * 4);
    int* rowptr = (int*)p;         p += align((size_t)N * 4);
    int* bsum = (int*)p;           p += align((size_t)nb * 4);
    float* dinv = (float*)p;       p += align((size_t)N * 4);
    int2* pairs = (int2*)p;        p += align((size_t)E * 8);
    unsigned short* Ahi = (unsigned short*)p;  p += align((size_t)Npad * 128 * 2);
    unsigned short* Alo = (unsigned short*)p;  p += align((size_t)Npad * 128 * 2);
    unsigned short* Thi = (unsigned short*)p;  p += align((size_t)Npad * 128 * 2);
    unsigned short* Tlo = (unsigned short*)p;  p += align((size_t)Npad * 128 * 2);
    unsigned short* W1h = (unsigned short*)p;  p += align(128 * 128 * 2);
    unsigned short* W1l = (unsigned short*)p;  p += align(128 * 128 * 2);
    unsigned short* W2h = (unsigned short*)p;  p += align(128 * 128 * 2);
    unsigned short* W2l = (unsigned short*)p;  p += align(128 * 128 * 2);
    unsigned short* W3h = (unsigned short*)p;  p += align(64 * 128 * 2);
    unsigned short* W3l = (unsigned short*)p;

    // ---- CSR build (once) ----
    hipMemsetAsync(cnt, 0, (size_t)N * 4, stream);
    cnt_k<<<(E + 255) / 256, 256, 0, stream>>>(dst, cnt, E);
    scan1_k<<<nb, 256, 0, stream>>>(cnt, bsum, dinv, N);
    scan2_k<<<1, 512, 0, stream>>>(bsum, nb);
    scan3_k<<<nb, 256, 0, stream>>>(cnt, bsum, rowptr, N);
    fill_k<<<(E + 255) / 256, 256, 0, stream>>>(src, dst, dinv, rowptr, pairs, E);
    // rowptr[i] now holds END of row i.

    convw3_k<<<160, 256, 0, stream>>>(W1, W2, W3, W1h, W1l, W2h, W2l, W3h, W3l);

    const int gemm_blocks = Npad / 128;
    const int gather_blocks = (N + 3) / 4;

    // Layer 1 (A = x fp32, split in-register)
    mfma_gemm<128, true><<<gemm_blocks, 256, 0, stream>>>(x, nullptr, nullptr,
                                                          W1h, W1l, Thi, Tlo, N);
    gather_k<128, true><<<gather_blocks, 256, 0, stream>>>(rowptr, pairs, dinv, Thi, Tlo,
                                                           b1, nullptr, Ahi, Alo, N);
    // Layer 2
    mfma_gemm<128, false><<<gemm_blocks, 256, 0, stream>>>(nullptr, Ahi, Alo,
                                                           W2h, W2l, Thi, Tlo, N);
    gather_k<128, true><<<gather_blocks, 256, 0, stream>>>(rowptr, pairs, dinv, Thi, Tlo,
                                                           b2, nullptr, Ahi, Alo, N);
    // Layer 3
    mfma_gemm<64, false><<<gemm_blocks, 256, 0, stream>>>(nullptr, Ahi, Alo,
                                                          W3h, W3l, Thi, Tlo, N);
    gather_k<64, false><<<gather_blocks, 256, 0, stream>>>(rowptr, pairs, dinv, Thi, Tlo,
                                                           b3, out, nullptr, nullptr, N);
}